// Round 1
// baseline (485.657 us; speedup 1.0000x reference)
//
#include <hip/hip_runtime.h>
#include <hip/hip_bf16.h>

// ---------------------------------------------------------------------------
// Compile-time construction of the 28x8 DWT composition matrix M:
//   y[k] = sum_j M[k][j] * patch[j],  k = [aa(7), ad(7), dd(7), da(7)]
// exactly matching pywt dwt mode='symmetric' applied twice (n=8 then n=7).
// ---------------------------------------------------------------------------
struct M28x8 { float m[28][8]; };

constexpr double DLO[8] = {-0.010597401784997278, 0.032883011666982945,
                            0.030841381835986965, -0.18703481171888114,
                           -0.02798376941698385,   0.6308807679295904,
                            0.7148465705525415,    0.23037781330885523};
constexpr double DHI[8] = {-0.23037781330885523,   0.7148465705525415,
                           -0.6308807679295904,   -0.02798376941698385,
                            0.18703481171888114,   0.030841381835986965,
                           -0.032883011666982945, -0.010597401784997278};

// out[i] = sum_j lo_rev[j] * ext[1+2i+j], ext = symmetric pad width 7
constexpr void dwt_c(const double* x, int n, double* lo, double* hi) {
    int out_len = (n + 7) / 2;
    for (int i = 0; i < out_len; ++i) {
        double a = 0.0, d = 0.0;
        for (int j = 0; j < 8; ++j) {
            int q = 2 * i + j - 6;           // position into x (may be OOB)
            if (q < 0) q = -q - 1;           // left symmetric reflect
            if (q >= n) q = 2 * n - 1 - q;   // right symmetric reflect
            a += DLO[7 - j] * x[q];
            d += DHI[7 - j] * x[q];
        }
        lo[i] = a; hi[i] = d;
    }
}

constexpr M28x8 build_M() {
    M28x8 R{};
    for (int j = 0; j < 8; ++j) {
        double x[8] = {0,0,0,0,0,0,0,0};
        x[j] = 1.0;
        double cA[7] = {}, cD[7] = {};
        dwt_c(x, 8, cA, cD);
        double aa[7] = {}, ad[7] = {}, da[7] = {}, dd[7] = {};
        dwt_c(cA, 7, aa, ad);
        dwt_c(cD, 7, da, dd);
        for (int i = 0; i < 7; ++i) {
            R.m[i][j]      = (float)aa[i];
            R.m[7 + i][j]  = (float)ad[i];
            R.m[14 + i][j] = (float)dd[i];   // note: dd before da in concat
            R.m[21 + i][j] = (float)da[i];
        }
    }
    return R;
}

__constant__ M28x8 g_M = build_M();

// ---------------------------------------------------------------------------
// Wfold[o][c][j] = sum_k W[o, c*28+k] * M[k][j]   -> 128*3*8 = 3072 floats
// ---------------------------------------------------------------------------
__global__ void wfold_kernel(const float* __restrict__ W, float* __restrict__ Wf) {
    int t = blockIdx.x * blockDim.x + threadIdx.x;
    if (t >= 128 * 24) return;
    int o = t / 24;
    int cj = t - o * 24;
    int c = cj >> 3;
    int j = cj & 7;
    const float* wr = W + o * 84 + c * 28;
    float acc = 0.f;
#pragma unroll
    for (int k = 0; k < 28; ++k) acc += wr[k] * g_M.m[k][j];
    Wf[t] = acc;
}

// ---------------------------------------------------------------------------
// Main kernel.
//   B=32, C=3, T=4096, V=25, P=1024, out (32, 25600, 128) fp32
//   out[b, v*1024 + p, o] = sum_{c,j} Wfold[o][c*8+j] * x[b,c,min(4p+j,4095),v]
// One block = (b, tile of 16 p values). LDS slab x[b,:,t0:t0+68,:] stored
// transposed as [c][v][t] so the 8-tap window = 2x ds_read_b128 per channel
// (wave-uniform address -> broadcast, conflict-free).
// ---------------------------------------------------------------------------
#define PT   16              // p values per block
#define TT   (4 * PT + 4)    // 68 t values per block
#define SLAB (3 * 25 * TT)   // 5100 floats = 20.4 KB LDS

__global__ __launch_bounds__(256) void wave_kernel(const float* __restrict__ x,
                                                   const float* __restrict__ Wf,
                                                   float* __restrict__ out) {
    __shared__ float s_x[SLAB];
    const int tile = blockIdx.x;       // 0..63
    const int b    = blockIdx.y;       // 0..31
    const int t0   = tile * (4 * PT);
    const int tid  = threadIdx.x;

    // stage global -> LDS (global reads are contiguous runs of 1700 floats/ch)
    for (int lin = tid; lin < SLAB; lin += 256) {
        int v  = lin % 25;
        int r  = lin / 25;       // c*TT + tt
        int tt = r % TT;
        int c  = r / TT;
        int t  = t0 + tt;
        if (t > 4095) t = 4095;  // edge padding of T by 4
        s_x[(c * 25 + v) * TT + tt] = x[((b * 3 + c) * 4096 + t) * 25 + v];
    }

    // per-thread weights: o = tid&127, 24 floats in registers
    const int o = tid & 127;
    const int s = tid >> 7;
    float w[24];
#pragma unroll
    for (int q = 0; q < 6; ++q) {
        float4 f = ((const float4*)(Wf + o * 24))[q];
        w[4 * q + 0] = f.x; w[4 * q + 1] = f.y;
        w[4 * q + 2] = f.z; w[4 * q + 3] = f.w;
    }

    __syncthreads();

    const int out_base = (b * 25600 + tile * PT) * 128 + o;
    for (int idx = s; idx < 25 * PT; idx += 2) {
        int v  = idx >> 4;       // PT == 16
        int pl = idx & 15;
        float acc = 0.f;
#pragma unroll
        for (int c = 0; c < 3; ++c) {
            const float4* row = (const float4*)(s_x + (c * 25 + v) * TT + 4 * pl);
            float4 a = row[0];
            float4 bq = row[1];
            acc += w[c*8+0]*a.x  + w[c*8+1]*a.y  + w[c*8+2]*a.z  + w[c*8+3]*a.w
                 + w[c*8+4]*bq.x + w[c*8+5]*bq.y + w[c*8+6]*bq.z + w[c*8+7]*bq.w;
        }
        out[out_base + (v * 1024 + pl) * 128] = acc;
    }
}

extern "C" void kernel_launch(void* const* d_in, const int* in_sizes, int n_in,
                              void* d_out, int out_size, void* d_ws, size_t ws_size,
                              hipStream_t stream) {
    const float* x = (const float*)d_in[0];   // (32, 3, 4096, 25) fp32
    const float* W = (const float*)d_in[1];   // (128, 84) fp32
    float* out = (float*)d_out;               // (32, 25600, 128) fp32
    float* Wf  = (float*)d_ws;                // 3072 floats scratch

    hipLaunchKernelGGL(wfold_kernel, dim3(12), dim3(256), 0, stream, W, Wf);
    hipLaunchKernelGGL(wave_kernel, dim3(64, 32), dim3(256), 0, stream, x, Wf, out);
}

// Round 2
// 460.304 us; speedup vs baseline: 1.0551x; 1.0551x over previous
//
#include <hip/hip_runtime.h>
#include <hip/hip_bf16.h>

// ---------------------------------------------------------------------------
// Compile-time construction of the 28x8 DWT composition matrix M:
//   y[k] = sum_j M[k][j] * patch[j],  k = [aa(7), ad(7), dd(7), da(7)]
// exactly matching pywt dwt mode='symmetric' applied twice (n=8 then n=7).
// ---------------------------------------------------------------------------
struct M28x8 { float m[28][8]; };

constexpr double DLO[8] = {-0.010597401784997278, 0.032883011666982945,
                            0.030841381835986965, -0.18703481171888114,
                           -0.02798376941698385,   0.6308807679295904,
                            0.7148465705525415,    0.23037781330885523};
constexpr double DHI[8] = {-0.23037781330885523,   0.7148465705525415,
                           -0.6308807679295904,   -0.02798376941698385,
                            0.18703481171888114,   0.030841381835986965,
                           -0.032883011666982945, -0.010597401784997278};

constexpr void dwt_c(const double* x, int n, double* lo, double* hi) {
    int out_len = (n + 7) / 2;
    for (int i = 0; i < out_len; ++i) {
        double a = 0.0, d = 0.0;
        for (int j = 0; j < 8; ++j) {
            int q = 2 * i + j - 6;
            if (q < 0) q = -q - 1;
            if (q >= n) q = 2 * n - 1 - q;
            a += DLO[7 - j] * x[q];
            d += DHI[7 - j] * x[q];
        }
        lo[i] = a; hi[i] = d;
    }
}

constexpr M28x8 build_M() {
    M28x8 R{};
    for (int j = 0; j < 8; ++j) {
        double x[8] = {0,0,0,0,0,0,0,0};
        x[j] = 1.0;
        double cA[7] = {}, cD[7] = {};
        dwt_c(x, 8, cA, cD);
        double aa[7] = {}, ad[7] = {}, da[7] = {}, dd[7] = {};
        dwt_c(cA, 7, aa, ad);
        dwt_c(cD, 7, da, dd);
        for (int i = 0; i < 7; ++i) {
            R.m[i][j]      = (float)aa[i];
            R.m[7 + i][j]  = (float)ad[i];
            R.m[14 + i][j] = (float)dd[i];   // dd before da in concat
            R.m[21 + i][j] = (float)da[i];
        }
    }
    return R;
}

__constant__ M28x8 g_M = build_M();

// ---------------------------------------------------------------------------
// Wfold[o][c*8+j] = sum_k W[o, c*28+k] * M[k][j]   -> 128*24 = 3072 floats
// ---------------------------------------------------------------------------
__global__ void wfold_kernel(const float* __restrict__ W, float* __restrict__ Wf) {
    int t = blockIdx.x * blockDim.x + threadIdx.x;
    if (t >= 128 * 24) return;
    int o = t / 24;
    int cj = t - o * 24;
    int c = cj >> 3;
    int j = cj & 7;
    const float* wr = W + o * 84 + c * 28;
    float acc = 0.f;
#pragma unroll
    for (int k = 0; k < 28; ++k) acc += wr[k] * g_M.m[k][j];
    Wf[t] = acc;
}

// ---------------------------------------------------------------------------
// Main kernel.
//   out[b, v*1024 + p, o] = sum_{c,j} Wfold[o][c*8+j] * x[b,c,min(4p+j,4095),v]
// Block = (b, 16-p tile). LDS slab x[b,:,t0:t0+68,:] stored [c][v][t].
// Each thread owns 4 consecutive o (96 weights in VGPRs) and iterates
// (v,pl) pairs in groups of 32 lanes -> per wave-iter: 6 ds_read_b128
// (2 distinct broadcast addrs, conflict-free) + 96 v_fmac + 1 dwordx4 store
// producing 256 outputs.
// ---------------------------------------------------------------------------
#define PT   16              // p values per block
#define TT   (4 * PT + 4)    // 68 t values
#define SLAB (3 * 25 * TT)   // 5100 floats = 20.4 KB LDS

__global__ __launch_bounds__(256, 2) void wave_kernel(const float* __restrict__ x,
                                                      const float* __restrict__ Wf,
                                                      float* __restrict__ out) {
    __shared__ float s_x[SLAB];
    const int tile = blockIdx.x;       // 0..63
    const int b    = blockIdx.y;       // 0..31
    const int t0   = tile * (4 * PT);
    const int tid  = threadIdx.x;

    // stage global -> LDS (coalesced; runs of 1700 contiguous floats per ch)
    for (int lin = tid; lin < SLAB; lin += 256) {
        int v  = lin % 25;
        int r  = lin / 25;       // c*TT + tt
        int tt = r % TT;
        int c  = r / TT;
        int t  = t0 + tt;
        if (t > 4095) t = 4095;  // edge padding (PAD=4)
        s_x[(c * 25 + v) * TT + tt] = x[((b * 3 + c) * 4096 + t) * 25 + v];
    }

    const int og  = tid & 31;          // o-group: o = og*4
    const int grp = tid >> 5;          // 0..7 -> which (v,pl) stream
    const int o   = og << 2;

    // 4 rows of 24 folded weights in registers (L1-resident global loads)
    float wr[4][24];
#pragma unroll
    for (int m = 0; m < 4; ++m) {
        const float4* wp = (const float4*)(Wf + (o + m) * 24);
#pragma unroll
        for (int q = 0; q < 6; ++q) {
            float4 f = wp[q];
            wr[m][4 * q + 0] = f.x; wr[m][4 * q + 1] = f.y;
            wr[m][4 * q + 2] = f.z; wr[m][4 * q + 3] = f.w;
        }
    }

    __syncthreads();

    const long out_blk = (long)(b * 25600 + tile * PT) * 128 + o;
    for (int idx = grp; idx < 25 * PT; idx += 8) {
        const int v  = idx >> 4;       // PT == 16
        const int pl = idx & 15;
        float acc[4] = {0.f, 0.f, 0.f, 0.f};
#pragma unroll
        for (int c = 0; c < 3; ++c) {
            const float4* row = (const float4*)(s_x + (c * 25 + v) * TT + 4 * pl);
            float4 xa = row[0];
            float4 xb = row[1];
#pragma unroll
            for (int m = 0; m < 4; ++m) {
                acc[m] += wr[m][c*8+0]*xa.x + wr[m][c*8+1]*xa.y
                        + wr[m][c*8+2]*xa.z + wr[m][c*8+3]*xa.w
                        + wr[m][c*8+4]*xb.x + wr[m][c*8+5]*xb.y
                        + wr[m][c*8+6]*xb.z + wr[m][c*8+7]*xb.w;
            }
        }
        float4 st = {acc[0], acc[1], acc[2], acc[3]};
        *(float4*)(out + out_blk + (long)(v * 1024 + pl) * 128) = st;
    }
}

extern "C" void kernel_launch(void* const* d_in, const int* in_sizes, int n_in,
                              void* d_out, int out_size, void* d_ws, size_t ws_size,
                              hipStream_t stream) {
    const float* x = (const float*)d_in[0];   // (32, 3, 4096, 25) fp32
    const float* W = (const float*)d_in[1];   // (128, 84) fp32
    float* out = (float*)d_out;               // (32, 25600, 128) fp32
    float* Wf  = (float*)d_ws;                // 3072 floats scratch

    hipLaunchKernelGGL(wfold_kernel, dim3(12), dim3(256), 0, stream, W, Wf);
    hipLaunchKernelGGL(wave_kernel, dim3(64, 32), dim3(256), 0, stream, x, Wf, out);
}